// Round 19
// baseline (1491.398 us; speedup 1.0000x reference)
//
#include <hip/hip_runtime.h>
#include <cstdint>
#include <cstddef>

#define B_   4
#define S_   2048
#define D_   2048
#define H_   16
#define DH_  128
#define DFF_ 8192
#define LOG2E 1.4426950408889634f

typedef __bf16 bf16_t;
typedef __bf16 bf16x4 __attribute__((ext_vector_type(4)));
typedef __bf16 bf16x8 __attribute__((ext_vector_type(8)));
typedef float  f32x4  __attribute__((ext_vector_type(4)));

#define MFMA16 __builtin_amdgcn_mfma_f32_16x16x32_bf16

__device__ __forceinline__ void glds16(const void* g, void* l) {
  __builtin_amdgcn_global_load_lds((__attribute__((address_space(1))) void*)g,
                                   (__attribute__((address_space(3))) void*)l,
                                   16, 0, 0);
}

// ---------------- fp32 -> bf16 convert, 8 elems/thread ----------------
__global__ __launch_bounds__(256) void cvt_kernel(const float* __restrict__ in,
                                                  bf16_t* __restrict__ out, int n8) {
  int i = blockIdx.x * 256 + threadIdx.x;
  if (i >= n8) return;
  const float4* p4 = (const float4*)in;
  float4 a = p4[2 * (size_t)i];
  float4 b = p4[2 * (size_t)i + 1];
  bf16x8 o;
  o[0] = (bf16_t)a.x; o[1] = (bf16_t)a.y; o[2] = (bf16_t)a.z; o[3] = (bf16_t)a.w;
  o[4] = (bf16_t)b.x; o[5] = (bf16_t)b.y; o[6] = (bf16_t)b.z; o[7] = (bf16_t)b.w;
  ((bf16x8*)out)[i] = o;
}

// ---------------- RMSNorm: fp32 [rows,2048] -> bf16 [rows,2048] ----------------
__global__ __launch_bounds__(256) void rmsnorm_kernel(const float* __restrict__ x,
                                                      const float* __restrict__ g,
                                                      bf16_t* __restrict__ out) {
  const int row = blockIdx.x, tid = threadIdx.x;
  const float* xr = x + (size_t)row * D_;
  float4 a = ((const float4*)xr)[tid * 2];
  float4 b = ((const float4*)xr)[tid * 2 + 1];
  float ss = a.x*a.x + a.y*a.y + a.z*a.z + a.w*a.w
           + b.x*b.x + b.y*b.y + b.z*b.z + b.w*b.w;
#pragma unroll
  for (int m = 1; m < 64; m <<= 1) ss += __shfl_xor(ss, m);
  __shared__ float red[4];
  if ((tid & 63) == 0) red[tid >> 6] = ss;
  __syncthreads();
  float tot = red[0] + red[1] + red[2] + red[3];
  float rms = rsqrtf(tot * (1.0f / D_) + 1e-5f);
  float4 ga = ((const float4*)g)[tid * 2];
  float4 gb = ((const float4*)g)[tid * 2 + 1];
  bf16x8 o;
  o[0] = (bf16_t)(a.x * rms * ga.x); o[1] = (bf16_t)(a.y * rms * ga.y);
  o[2] = (bf16_t)(a.z * rms * ga.z); o[3] = (bf16_t)(a.w * rms * ga.w);
  o[4] = (bf16_t)(b.x * rms * gb.x); o[5] = (bf16_t)(b.y * rms * gb.y);
  o[6] = (bf16_t)(b.z * rms * gb.z); o[7] = (bf16_t)(b.w * rms * gb.w);
  ((bf16x8*)out)[(size_t)row * 256 + tid] = o;
}

// ====== gemm256h: 128x256 tile, 64x64/wave, single-buffer 48KB, BK=64 =======
// 2 blocks/CU; inter-block overlap covers the per-tile stage drain.
// 128B rows + (row&7)<<4 XOR swizzle (both sides) — conflict-free.
// EPI 0: bf16.  EPI 1: fp32 + addf.  EPI 2: silu(addb)*acc.
// EPI 4: fused QKV + RoPE: seg 0 -> outb (q, rotated), seg 1 -> outb2 (k,
//        rotated), seg 2 -> outb3 = V^T pack vt[b][n][s].
template <int EPI>
__global__ __launch_bounds__(512, 4) void gemm256h(const bf16_t* __restrict__ A,
                                                   const bf16_t* __restrict__ W,
                                                   const float* __restrict__ addf,
                                                   const bf16_t* __restrict__ addb,
                                                   bf16_t* __restrict__ outb,
                                                   bf16_t* __restrict__ outb2,
                                                   bf16_t* __restrict__ outb3,
                                                   float* __restrict__ outf,
                                                   int M, int N, int K) {
  __shared__ char ldsb[49152];   // A [128][128B] @0, B [256][128B] @16384
  const int tid = threadIdx.x;
  const int wid = tid >> 6, l = tid & 63, l15 = l & 15, lg = l >> 4;
  const int wm = wid >> 2, wn = wid & 3;

  const int nwg = gridDim.x;
  int wg = (int)blockIdx.x;
  wg = (wg & 7) * (nwg >> 3) + (wg >> 3);
  const int ntm = M >> 7;
  const int wide = 4 * ntm;
  const int grp = wg / wide;
  const int rem = wg % wide;
  const int m0 = (rem >> 2) << 7;
  const int n0 = ((grp << 2) + (rem & 3)) << 8;

  f32x4 acc[4][4];
  const f32x4 z4 = {0.f, 0.f, 0.f, 0.f};
#pragma unroll
  for (int i = 0; i < 4; i++)
#pragma unroll
    for (int j = 0; j < 4; j++) acc[i][j] = z4;

  const int o0 = tid * 16;
  const int srow = o0 >> 7;                               // 0..63
  const int ssw = ((o0 & 127) ^ ((srow & 7) << 4)) >> 1;  // swizzled src col
  const bf16_t* Asrc = A + (size_t)(m0 + srow) * K + ssw;
  const bf16_t* Wsrc = W + (size_t)(n0 + srow) * K + ssw;
  const int rsw = (l15 & 7) << 4;
  const int acol0 = (lg * 16) ^ rsw;
  const int acol1 = (64 + lg * 16) ^ rsw;

  const int NT = K >> 6;
  for (int t = 0; t < NT; t++) {
    const bf16_t* as = Asrc + (size_t)t * 64;
    glds16(as, ldsb + o0);
    glds16(as + 64 * (size_t)K, ldsb + 8192 + o0);
    const bf16_t* ws = Wsrc + (size_t)t * 64;
    glds16(ws, ldsb + 16384 + o0);
    glds16(ws + 64 * (size_t)K, ldsb + 24576 + o0);
    glds16(ws + 128 * (size_t)K, ldsb + 32768 + o0);
    glds16(ws + 192 * (size_t)K, ldsb + 40960 + o0);
    asm volatile("s_waitcnt vmcnt(0)" ::: "memory");
    __builtin_amdgcn_s_barrier();
    __builtin_amdgcn_sched_barrier(0);
    bf16x8 af[4][2];
#pragma unroll
    for (int fi = 0; fi < 4; fi++) {
      const char* p = ldsb + (wm * 64 + fi * 16 + l15) * 128;
      af[fi][0] = *(const bf16x8*)(p + acol0);
      af[fi][1] = *(const bf16x8*)(p + acol1);
    }
    __builtin_amdgcn_s_setprio(1);
#pragma unroll
    for (int n = 0; n < 4; n++) {
      const char* p = ldsb + 16384 + (wn * 64 + n * 16 + l15) * 128;
      bf16x8 b0 = *(const bf16x8*)(p + acol0);
      bf16x8 b1 = *(const bf16x8*)(p + acol1);
#pragma unroll
      for (int m = 0; m < 4; m++) {
        acc[m][n] = MFMA16(af[m][0], b0, acc[m][n], 0, 0, 0);
        acc[m][n] = MFMA16(af[m][1], b1, acc[m][n], 0, 0, 0);
      }
    }
    __builtin_amdgcn_s_setprio(0);
    __builtin_amdgcn_sched_barrier(0);
    __builtin_amdgcn_s_barrier();
  }

#pragma unroll
  for (int m = 0; m < 4; m++) {
    const int gr = m0 + wm * 64 + m * 16 + lg * 4;
#pragma unroll
    for (int n = 0; n < 4; n++) {
      const int gc = n0 + wn * 64 + n * 16 + l15;
      if constexpr (EPI == 4) {
        const int seg = gc >> 11;       // uniform per block
        const int gcl = gc & 2047;
        if (seg < 2) {
          // ---- fused RoPE: partner column gc^1 lives in lane l15^1 ----
          bf16_t* o = seg ? outb2 : outb;
          const int d = gcl & 127;
          const float inv = expf((float)(d >> 1) * (-9.210340371976184f / 64.0f));
          const bool oddc = (gcl & 1);
#pragma unroll
          for (int r = 0; r < 4; r++) {
            float v = acc[m][n][r];
            float vp = __shfl_xor(v, 1);
            float ang = (float)((gr + r) & 2047) * inv;
            float c = cosf(ang), sn = sinf(ang);
            float res = oddc ? (vp * sn + v * c) : (v * c - vp * sn);
            o[(size_t)(gr + r) * D_ + gcl] = (bf16_t)res;
          }
        } else {
          const int bb = gr >> 11, ss = gr & 2047;
          bf16x4 pk;
#pragma unroll
          for (int r = 0; r < 4; r++) pk[r] = (bf16_t)acc[m][n][r];
          *(bf16x4*)(outb3 + ((size_t)bb * D_ + gcl) * S_ + ss) = pk;
        }
      } else {
#pragma unroll
        for (int r = 0; r < 4; r++) {
          size_t idx = (size_t)(gr + r) * N + gc;
          if constexpr (EPI == 0) {
            outb[idx] = (bf16_t)acc[m][n][r];
          } else if constexpr (EPI == 1) {
            outf[idx] = acc[m][n][r] + addf[idx];
          } else {
            float a1v = (float)addb[idx];
            outb[idx] = (bf16_t)(a1v / (1.0f + expf(-a1v)) * acc[m][n][r]);
          }
        }
      }
    }
  }
}

// ---------------- Flash attention, KV tile = 64 (non-causal) -----------------
// grid (S/64, H, B), 4 waves x 16 q-rows. exp2 softmax, defer-max (THR=8),
// packed bf16x4 P-writes.
__global__ __launch_bounds__(256) void attn_kernel(const bf16_t* __restrict__ Q,
                                                   const bf16_t* __restrict__ Kb,
                                                   const bf16_t* __restrict__ Vt,
                                                   bf16_t* __restrict__ O) {
  const int qt = blockIdx.x, h = blockIdx.y, b = blockIdx.z;
  const int tid = threadIdx.x;
  const int wid = tid >> 6, l = tid & 63, l15 = l & 15, lg = l >> 4;

  __shared__ bf16_t Klds[64 * 128];      // [kv][dh] 256B rows, swz (row&7)<<4
  __shared__ bf16_t Vlds[128 * 64];      // V^T [dh][kv] 128B rows, swz (row&7)<<4
  __shared__ bf16_t Plds[4][16 * 72];    // per-wave P [q][kv64], stride 72

  const int q0 = qt * 64 + wid * 16;
  const f32x4 z4 = {0.f, 0.f, 0.f, 0.f};
  const float SCL = 0.08838834764831845f * LOG2E;  // fold 1/sqrt(DH) * log2e

  bf16x8 qf[4];
  {
    const bf16_t* qp = Q + ((size_t)(b * S_ + q0 + l15)) * D_ + h * DH_ + lg * 8;
#pragma unroll
    for (int kk = 0; kk < 4; kk++) qf[kk] = *(const bf16x8*)(qp + kk * 32);
  }
  f32x4 of[8];
#pragma unroll
  for (int f = 0; f < 8; f++) of[f] = z4;
  float m_run = -1e30f, l_run = 0.f;

  const int o0 = tid * 16;
  const int krow0 = o0 >> 8;
  const int scol = ((o0 & 255) ^ ((krow0 & 7) << 4)) >> 1;
  const int vrow0 = o0 >> 7;
  const int vcol = ((o0 & 127) ^ ((vrow0 & 7) << 4)) >> 1;

  const size_t bh_off = ((size_t)b * S_) * D_ + (size_t)h * DH_;
  const bf16_t* vtbase = Vt + ((size_t)b * D_ + h * DH_) * S_;

  for (int kv0 = 0; kv0 < S_; kv0 += 64) {
    const bf16_t* kbase = Kb + bh_off + (size_t)kv0 * D_;
#pragma unroll
    for (int s = 0; s < 4; s++)
      glds16(kbase + (size_t)(krow0 + 16 * s) * D_ + scol,
             (char*)Klds + s * 4096 + wid * 1024);
#pragma unroll
    for (int s = 0; s < 4; s++)
      glds16(vtbase + (size_t)(vrow0 + 32 * s) * S_ + kv0 + vcol,
             (char*)Vlds + s * 4096 + wid * 1024);
    __syncthreads();

    f32x4 st[4];
#pragma unroll
    for (int c = 0; c < 4; c++) {
      st[c] = z4;
      const int row = c * 16 + l15;
      const char* kr = (const char*)Klds + row * 256;
      const int sw = (row & 7) << 4;
#pragma unroll
      for (int kk = 0; kk < 4; kk++) {
        bf16x8 kf = *(const bf16x8*)(kr + ((kk * 64 + lg * 16) ^ sw));
        st[c] = MFMA16(kf, qf[kk], st[c], 0, 0, 0);
      }
    }

    float s[16];
#pragma unroll
    for (int c = 0; c < 4; c++)
#pragma unroll
      for (int r = 0; r < 4; r++) s[c * 4 + r] = st[c][r] * SCL;
    float pm = s[0];
#pragma unroll
    for (int i = 1; i < 16; i++) pm = fmaxf(pm, s[i]);
    pm = fmaxf(pm, __shfl_xor(pm, 16));
    pm = fmaxf(pm, __shfl_xor(pm, 32));
    if (!__all(pm - m_run <= 8.0f)) {
      float mnew = fmaxf(m_run, pm);
      float alpha = exp2f(m_run - mnew);
      float aq[4];
#pragma unroll
      for (int r = 0; r < 4; r++) aq[r] = __shfl(alpha, lg * 4 + r);
#pragma unroll
      for (int f = 0; f < 8; f++)
#pragma unroll
        for (int r = 0; r < 4; r++) of[f][r] *= aq[r];
      l_run *= alpha;
      m_run = mnew;
    }
    float p[16], ts = 0.f;
#pragma unroll
    for (int i = 0; i < 16; i++) { p[i] = exp2f(s[i] - m_run); ts += p[i]; }
    ts += __shfl_xor(ts, 16);
    ts += __shfl_xor(ts, 32);
    l_run += ts;

    bf16_t* pw = &Plds[wid][0];
#pragma unroll
    for (int c = 0; c < 4; c++) {
      bf16x4 pk;
#pragma unroll
      for (int r = 0; r < 4; r++) pk[r] = (bf16_t)p[c * 4 + r];
      *(bf16x4*)(pw + l15 * 72 + c * 16 + lg * 4) = pk;
    }
    asm volatile("s_waitcnt lgkmcnt(0)" ::: "memory");
    bf16x8 pa0 = *(const bf16x8*)(pw + l15 * 72 + lg * 8);
    bf16x8 pa1 = *(const bf16x8*)(pw + l15 * 72 + 32 + lg * 8);
#pragma unroll
    for (int f = 0; f < 8; f++) {
      const int row = 16 * f + l15;
      const char* vr = (const char*)Vlds + row * 128;
      const int sw = (row & 7) << 4;
      bf16x8 bv0 = *(const bf16x8*)(vr + ((lg * 16) ^ sw));
      bf16x8 bv1 = *(const bf16x8*)(vr + ((64 + lg * 16) ^ sw));
      of[f] = MFMA16(pa0, bv0, of[f], 0, 0, 0);
      of[f] = MFMA16(pa1, bv1, of[f], 0, 0, 0);
    }
    __syncthreads();
  }

  float inv[4];
#pragma unroll
  for (int r = 0; r < 4; r++) inv[r] = 1.0f / __shfl(l_run, lg * 4 + r);
#pragma unroll
  for (int f = 0; f < 8; f++)
#pragma unroll
    for (int r = 0; r < 4; r++)
      O[((size_t)(b * S_ + q0 + lg * 4 + r)) * D_ + h * DH_ + 16 * f + l15] =
          (bf16_t)(of[f][r] * inv[r]);
}

// =============================== launch ======================================
extern "C" void kernel_launch(void* const* d_in, const int* in_sizes, int n_in,
                              void* d_out, int out_size, void* d_ws, size_t ws_size,
                              hipStream_t stream) {
  const float* x  = (const float*)d_in[0];
  const float* wq = (const float*)d_in[2];
  const float* wk = (const float*)d_in[3];
  const float* wv = (const float*)d_in[4];
  const float* wo = (const float*)d_in[5];
  const float* w1 = (const float*)d_in[6];
  const float* w2 = (const float*)d_in[7];
  const float* w3 = (const float*)d_in[8];
  const float* g1 = (const float*)d_in[9];
  const float* g2 = (const float*)d_in[10];
  float* out = (float*)d_out;

  const size_t ND = (size_t)D_ * D_;
  const size_t NF = (size_t)DFF_ * D_;
  const size_t SLOT = NF * 2;               // 32 MiB
  char* base = (char*)d_ws;
  bf16_t* wslot = (bf16_t*)(base);
  bf16_t* h1    = (bf16_t*)(base + 1 * SLOT);
  bf16_t* qb    = (bf16_t*)(base + 2 * SLOT);
  bf16_t* kb    = (bf16_t*)(base + 3 * SLOT);
  bf16_t* vt    = (bf16_t*)(base + 4 * SLOT);
  bf16_t* ob    = (bf16_t*)(base + 5 * SLOT);
  bf16_t* h2    = h1;
  bf16_t* g     = qb;
  float*  x1    = out;

  auto cvt = [&](const float* in, bf16_t* o, size_t n) {
    int n8 = (int)(n / 8);
    cvt_kernel<<<(n8 + 255) / 256, 256, 0, stream>>>(in, o, n8);
  };

  rmsnorm_kernel<<<B_ * S_, 256, 0, stream>>>(x, g1, h1);

  // fused QKV + RoPE: [rope(q) | rope(k) | v^T] = h1 @ [wq;wk;wv]^T
  cvt(wq, wslot, ND);
  cvt(wk, wslot + ND, ND);
  cvt(wv, wslot + 2 * ND, ND);
  const int gqkv3 = (8192 / 128) * (6144 / 256);   // 1536 blocks
  gemm256h<4><<<gqkv3, 512, 0, stream>>>(h1, wslot, nullptr, nullptr,
                                         qb, kb, vt, nullptr, 8192, 6144, 2048);

  dim3 ga(S_ / 64, H_, B_);
  attn_kernel<<<ga, 256, 0, stream>>>(qb, kb, vt, ob);

  const int gd = (8192 / 128) * (2048 / 256);      // 512 blocks
  cvt(wo, wslot, ND);
  gemm256h<1><<<gd, 512, 0, stream>>>(ob, wslot, x, nullptr,
                                      nullptr, nullptr, nullptr, x1, 8192, 2048, 2048);

  rmsnorm_kernel<<<B_ * S_, 256, 0, stream>>>(x1, g2, h2);

  const int gffh = (8192 / 128) * (8192 / 256);    // 2048 blocks
  cvt(w1, wslot, NF);
  gemm256h<0><<<gffh, 512, 0, stream>>>(h2, wslot, nullptr, nullptr,
                                        g, nullptr, nullptr, nullptr, 8192, 8192, 2048);

  cvt(w3, wslot, NF);
  gemm256h<2><<<gffh, 512, 0, stream>>>(h2, wslot, nullptr, g,
                                        g, nullptr, nullptr, nullptr, 8192, 8192, 2048);

  cvt(w2, wslot, NF);
  gemm256h<1><<<gd, 512, 0, stream>>>(g, wslot, x1, nullptr,
                                      nullptr, nullptr, nullptr, x1, 8192, 2048, 8192);
}

// Round 20
// 1373.897 us; speedup vs baseline: 1.0855x; 1.0855x over previous
//
#include <hip/hip_runtime.h>
#include <cstdint>
#include <cstddef>

#define B_   4
#define S_   2048
#define D_   2048
#define H_   16
#define DH_  128
#define DFF_ 8192
#define LOG2E 1.4426950408889634f

typedef __bf16 bf16_t;
typedef __bf16 bf16x4 __attribute__((ext_vector_type(4)));
typedef __bf16 bf16x8 __attribute__((ext_vector_type(8)));
typedef float  f32x4  __attribute__((ext_vector_type(4)));

#define MFMA16 __builtin_amdgcn_mfma_f32_16x16x32_bf16

__device__ __forceinline__ void glds16(const void* g, void* l) {
  __builtin_amdgcn_global_load_lds((__attribute__((address_space(1))) void*)g,
                                   (__attribute__((address_space(3))) void*)l,
                                   16, 0, 0);
}

// ---------------- fp32 -> bf16 convert, 8 elems/thread ----------------
__global__ __launch_bounds__(256) void cvt_kernel(const float* __restrict__ in,
                                                  bf16_t* __restrict__ out, int n8) {
  int i = blockIdx.x * 256 + threadIdx.x;
  if (i >= n8) return;
  const float4* p4 = (const float4*)in;
  float4 a = p4[2 * (size_t)i];
  float4 b = p4[2 * (size_t)i + 1];
  bf16x8 o;
  o[0] = (bf16_t)a.x; o[1] = (bf16_t)a.y; o[2] = (bf16_t)a.z; o[3] = (bf16_t)a.w;
  o[4] = (bf16_t)b.x; o[5] = (bf16_t)b.y; o[6] = (bf16_t)b.z; o[7] = (bf16_t)b.w;
  ((bf16x8*)out)[i] = o;
}

// ---------------- RMSNorm: fp32 [rows,2048] -> bf16 [rows,2048] ----------------
__global__ __launch_bounds__(256) void rmsnorm_kernel(const float* __restrict__ x,
                                                      const float* __restrict__ g,
                                                      bf16_t* __restrict__ out) {
  const int row = blockIdx.x, tid = threadIdx.x;
  const float* xr = x + (size_t)row * D_;
  float4 a = ((const float4*)xr)[tid * 2];
  float4 b = ((const float4*)xr)[tid * 2 + 1];
  float ss = a.x*a.x + a.y*a.y + a.z*a.z + a.w*a.w
           + b.x*b.x + b.y*b.y + b.z*b.z + b.w*b.w;
#pragma unroll
  for (int m = 1; m < 64; m <<= 1) ss += __shfl_xor(ss, m);
  __shared__ float red[4];
  if ((tid & 63) == 0) red[tid >> 6] = ss;
  __syncthreads();
  float tot = red[0] + red[1] + red[2] + red[3];
  float rms = rsqrtf(tot * (1.0f / D_) + 1e-5f);
  float4 ga = ((const float4*)g)[tid * 2];
  float4 gb = ((const float4*)g)[tid * 2 + 1];
  bf16x8 o;
  o[0] = (bf16_t)(a.x * rms * ga.x); o[1] = (bf16_t)(a.y * rms * ga.y);
  o[2] = (bf16_t)(a.z * rms * ga.z); o[3] = (bf16_t)(a.w * rms * ga.w);
  o[4] = (bf16_t)(b.x * rms * gb.x); o[5] = (bf16_t)(b.y * rms * gb.y);
  o[6] = (bf16_t)(b.z * rms * gb.z); o[7] = (bf16_t)(b.w * rms * gb.w);
  ((bf16x8*)out)[(size_t)row * 256 + tid] = o;
}

// ====== gemm256h: 128x256 tile, 64x64/wave, single-buffer 48KB, BK=64 =======
// 2 blocks/CU; inter-block overlap covers the per-tile stage drain.
// 128B rows + (row&7)<<4 XOR swizzle (both sides) — conflict-free.
// EPI 0: bf16.  EPI 1: fp32 + addf.  EPI 2: silu(addb)*acc.
// EPI 4: fused QKV + RoPE (hardware trig): seg 0 -> outb (q, rotated),
//        seg 1 -> outb2 (k, rotated), seg 2 -> outb3 = V^T pack vt[b][n][s].
template <int EPI>
__global__ __launch_bounds__(512, 4) void gemm256h(const bf16_t* __restrict__ A,
                                                   const bf16_t* __restrict__ W,
                                                   const float* __restrict__ addf,
                                                   const bf16_t* __restrict__ addb,
                                                   bf16_t* __restrict__ outb,
                                                   bf16_t* __restrict__ outb2,
                                                   bf16_t* __restrict__ outb3,
                                                   float* __restrict__ outf,
                                                   int M, int N, int K) {
  __shared__ char ldsb[49152];   // A [128][128B] @0, B [256][128B] @16384
  const int tid = threadIdx.x;
  const int wid = tid >> 6, l = tid & 63, l15 = l & 15, lg = l >> 4;
  const int wm = wid >> 2, wn = wid & 3;

  const int nwg = gridDim.x;
  int wg = (int)blockIdx.x;
  wg = (wg & 7) * (nwg >> 3) + (wg >> 3);
  const int ntm = M >> 7;
  const int wide = 4 * ntm;
  const int grp = wg / wide;
  const int rem = wg % wide;
  const int m0 = (rem >> 2) << 7;
  const int n0 = ((grp << 2) + (rem & 3)) << 8;

  f32x4 acc[4][4];
  const f32x4 z4 = {0.f, 0.f, 0.f, 0.f};
#pragma unroll
  for (int i = 0; i < 4; i++)
#pragma unroll
    for (int j = 0; j < 4; j++) acc[i][j] = z4;

  const int o0 = tid * 16;
  const int srow = o0 >> 7;                               // 0..63
  const int ssw = ((o0 & 127) ^ ((srow & 7) << 4)) >> 1;  // swizzled src col
  const bf16_t* Asrc = A + (size_t)(m0 + srow) * K + ssw;
  const bf16_t* Wsrc = W + (size_t)(n0 + srow) * K + ssw;
  const int rsw = (l15 & 7) << 4;
  const int acol0 = (lg * 16) ^ rsw;
  const int acol1 = (64 + lg * 16) ^ rsw;

  const int NT = K >> 6;
  for (int t = 0; t < NT; t++) {
    const bf16_t* as = Asrc + (size_t)t * 64;
    glds16(as, ldsb + o0);
    glds16(as + 64 * (size_t)K, ldsb + 8192 + o0);
    const bf16_t* ws = Wsrc + (size_t)t * 64;
    glds16(ws, ldsb + 16384 + o0);
    glds16(ws + 64 * (size_t)K, ldsb + 24576 + o0);
    glds16(ws + 128 * (size_t)K, ldsb + 32768 + o0);
    glds16(ws + 192 * (size_t)K, ldsb + 40960 + o0);
    asm volatile("s_waitcnt vmcnt(0)" ::: "memory");
    __builtin_amdgcn_s_barrier();
    __builtin_amdgcn_sched_barrier(0);
    bf16x8 af[4][2];
#pragma unroll
    for (int fi = 0; fi < 4; fi++) {
      const char* p = ldsb + (wm * 64 + fi * 16 + l15) * 128;
      af[fi][0] = *(const bf16x8*)(p + acol0);
      af[fi][1] = *(const bf16x8*)(p + acol1);
    }
    __builtin_amdgcn_s_setprio(1);
#pragma unroll
    for (int n = 0; n < 4; n++) {
      const char* p = ldsb + 16384 + (wn * 64 + n * 16 + l15) * 128;
      bf16x8 b0 = *(const bf16x8*)(p + acol0);
      bf16x8 b1 = *(const bf16x8*)(p + acol1);
#pragma unroll
      for (int m = 0; m < 4; m++) {
        acc[m][n] = MFMA16(af[m][0], b0, acc[m][n], 0, 0, 0);
        acc[m][n] = MFMA16(af[m][1], b1, acc[m][n], 0, 0, 0);
      }
    }
    __builtin_amdgcn_s_setprio(0);
    __builtin_amdgcn_sched_barrier(0);
    __builtin_amdgcn_s_barrier();
  }

#pragma unroll
  for (int m = 0; m < 4; m++) {
    const int gr = m0 + wm * 64 + m * 16 + lg * 4;
#pragma unroll
    for (int n = 0; n < 4; n++) {
      const int gc = n0 + wn * 64 + n * 16 + l15;
      if constexpr (EPI == 4) {
        const int seg = gc >> 11;       // uniform per block
        const int gcl = gc & 2047;
        if (seg < 2) {
          // ---- fused RoPE (hardware trig): partner col gc^1 = lane l15^1 ----
          bf16_t* o = seg ? outb2 : outb;
          const int d = gcl & 127;
          const float inv = __expf((float)(d >> 1) * (-9.210340371976184f / 64.0f));
          const bool oddc = (gcl & 1);
#pragma unroll
          for (int r = 0; r < 4; r++) {
            float v = acc[m][n][r];
            float vp = __shfl_xor(v, 1);
            float ang = (float)((gr + r) & 2047) * inv;
            float c = __cosf(ang), sn = __sinf(ang);
            float res = oddc ? (vp * sn + v * c) : (v * c - vp * sn);
            o[(size_t)(gr + r) * D_ + gcl] = (bf16_t)res;
          }
        } else {
          const int bb = gr >> 11, ss = gr & 2047;
          bf16x4 pk;
#pragma unroll
          for (int r = 0; r < 4; r++) pk[r] = (bf16_t)acc[m][n][r];
          *(bf16x4*)(outb3 + ((size_t)bb * D_ + gcl) * S_ + ss) = pk;
        }
      } else {
#pragma unroll
        for (int r = 0; r < 4; r++) {
          size_t idx = (size_t)(gr + r) * N + gc;
          if constexpr (EPI == 0) {
            outb[idx] = (bf16_t)acc[m][n][r];
          } else if constexpr (EPI == 1) {
            outf[idx] = acc[m][n][r] + addf[idx];
          } else {
            float a1v = (float)addb[idx];
            outb[idx] = (bf16_t)(a1v / (1.0f + expf(-a1v)) * acc[m][n][r]);
          }
        }
      }
    }
  }
}

// ---------------- Flash attention, KV tile = 64 (non-causal) -----------------
// grid (S/64, H, B), 4 waves x 16 q-rows. exp2 softmax, defer-max (THR=8),
// packed bf16x4 P-writes.
__global__ __launch_bounds__(256) void attn_kernel(const bf16_t* __restrict__ Q,
                                                   const bf16_t* __restrict__ Kb,
                                                   const bf16_t* __restrict__ Vt,
                                                   bf16_t* __restrict__ O) {
  const int qt = blockIdx.x, h = blockIdx.y, b = blockIdx.z;
  const int tid = threadIdx.x;
  const int wid = tid >> 6, l = tid & 63, l15 = l & 15, lg = l >> 4;

  __shared__ bf16_t Klds[64 * 128];      // [kv][dh] 256B rows, swz (row&7)<<4
  __shared__ bf16_t Vlds[128 * 64];      // V^T [dh][kv] 128B rows, swz (row&7)<<4
  __shared__ bf16_t Plds[4][16 * 72];    // per-wave P [q][kv64], stride 72

  const int q0 = qt * 64 + wid * 16;
  const f32x4 z4 = {0.f, 0.f, 0.f, 0.f};
  const float SCL = 0.08838834764831845f * LOG2E;  // fold 1/sqrt(DH) * log2e

  bf16x8 qf[4];
  {
    const bf16_t* qp = Q + ((size_t)(b * S_ + q0 + l15)) * D_ + h * DH_ + lg * 8;
#pragma unroll
    for (int kk = 0; kk < 4; kk++) qf[kk] = *(const bf16x8*)(qp + kk * 32);
  }
  f32x4 of[8];
#pragma unroll
  for (int f = 0; f < 8; f++) of[f] = z4;
  float m_run = -1e30f, l_run = 0.f;

  const int o0 = tid * 16;
  const int krow0 = o0 >> 8;
  const int scol = ((o0 & 255) ^ ((krow0 & 7) << 4)) >> 1;
  const int vrow0 = o0 >> 7;
  const int vcol = ((o0 & 127) ^ ((vrow0 & 7) << 4)) >> 1;

  const size_t bh_off = ((size_t)b * S_) * D_ + (size_t)h * DH_;
  const bf16_t* vtbase = Vt + ((size_t)b * D_ + h * DH_) * S_;

  for (int kv0 = 0; kv0 < S_; kv0 += 64) {
    const bf16_t* kbase = Kb + bh_off + (size_t)kv0 * D_;
#pragma unroll
    for (int s = 0; s < 4; s++)
      glds16(kbase + (size_t)(krow0 + 16 * s) * D_ + scol,
             (char*)Klds + s * 4096 + wid * 1024);
#pragma unroll
    for (int s = 0; s < 4; s++)
      glds16(vtbase + (size_t)(vrow0 + 32 * s) * S_ + kv0 + vcol,
             (char*)Vlds + s * 4096 + wid * 1024);
    __syncthreads();

    f32x4 st[4];
#pragma unroll
    for (int c = 0; c < 4; c++) {
      st[c] = z4;
      const int row = c * 16 + l15;
      const char* kr = (const char*)Klds + row * 256;
      const int sw = (row & 7) << 4;
#pragma unroll
      for (int kk = 0; kk < 4; kk++) {
        bf16x8 kf = *(const bf16x8*)(kr + ((kk * 64 + lg * 16) ^ sw));
        st[c] = MFMA16(kf, qf[kk], st[c], 0, 0, 0);
      }
    }

    float s[16];
#pragma unroll
    for (int c = 0; c < 4; c++)
#pragma unroll
      for (int r = 0; r < 4; r++) s[c * 4 + r] = st[c][r] * SCL;
    float pm = s[0];
#pragma unroll
    for (int i = 1; i < 16; i++) pm = fmaxf(pm, s[i]);
    pm = fmaxf(pm, __shfl_xor(pm, 16));
    pm = fmaxf(pm, __shfl_xor(pm, 32));
    if (!__all(pm - m_run <= 8.0f)) {
      float mnew = fmaxf(m_run, pm);
      float alpha = exp2f(m_run - mnew);
      float aq[4];
#pragma unroll
      for (int r = 0; r < 4; r++) aq[r] = __shfl(alpha, lg * 4 + r);
#pragma unroll
      for (int f = 0; f < 8; f++)
#pragma unroll
        for (int r = 0; r < 4; r++) of[f][r] *= aq[r];
      l_run *= alpha;
      m_run = mnew;
    }
    float p[16], ts = 0.f;
#pragma unroll
    for (int i = 0; i < 16; i++) { p[i] = exp2f(s[i] - m_run); ts += p[i]; }
    ts += __shfl_xor(ts, 16);
    ts += __shfl_xor(ts, 32);
    l_run += ts;

    bf16_t* pw = &Plds[wid][0];
#pragma unroll
    for (int c = 0; c < 4; c++) {
      bf16x4 pk;
#pragma unroll
      for (int r = 0; r < 4; r++) pk[r] = (bf16_t)p[c * 4 + r];
      *(bf16x4*)(pw + l15 * 72 + c * 16 + lg * 4) = pk;
    }
    asm volatile("s_waitcnt lgkmcnt(0)" ::: "memory");
    bf16x8 pa0 = *(const bf16x8*)(pw + l15 * 72 + lg * 8);
    bf16x8 pa1 = *(const bf16x8*)(pw + l15 * 72 + 32 + lg * 8);
#pragma unroll
    for (int f = 0; f < 8; f++) {
      const int row = 16 * f + l15;
      const char* vr = (const char*)Vlds + row * 128;
      const int sw = (row & 7) << 4;
      bf16x8 bv0 = *(const bf16x8*)(vr + ((lg * 16) ^ sw));
      bf16x8 bv1 = *(const bf16x8*)(vr + ((64 + lg * 16) ^ sw));
      of[f] = MFMA16(pa0, bv0, of[f], 0, 0, 0);
      of[f] = MFMA16(pa1, bv1, of[f], 0, 0, 0);
    }
    __syncthreads();
  }

  float inv[4];
#pragma unroll
  for (int r = 0; r < 4; r++) inv[r] = 1.0f / __shfl(l_run, lg * 4 + r);
#pragma unroll
  for (int f = 0; f < 8; f++)
#pragma unroll
    for (int r = 0; r < 4; r++)
      O[((size_t)(b * S_ + q0 + lg * 4 + r)) * D_ + h * DH_ + 16 * f + l15] =
          (bf16_t)(of[f][r] * inv[r]);
}

// =============================== launch ======================================
extern "C" void kernel_launch(void* const* d_in, const int* in_sizes, int n_in,
                              void* d_out, int out_size, void* d_ws, size_t ws_size,
                              hipStream_t stream) {
  const float* x  = (const float*)d_in[0];
  const float* wq = (const float*)d_in[2];
  const float* wk = (const float*)d_in[3];
  const float* wv = (const float*)d_in[4];
  const float* wo = (const float*)d_in[5];
  const float* w1 = (const float*)d_in[6];
  const float* w2 = (const float*)d_in[7];
  const float* w3 = (const float*)d_in[8];
  const float* g1 = (const float*)d_in[9];
  const float* g2 = (const float*)d_in[10];
  float* out = (float*)d_out;

  const size_t ND = (size_t)D_ * D_;
  const size_t NF = (size_t)DFF_ * D_;
  const size_t SLOT = NF * 2;               // 32 MiB
  char* base = (char*)d_ws;
  bf16_t* wslot = (bf16_t*)(base);
  bf16_t* h1    = (bf16_t*)(base + 1 * SLOT);
  bf16_t* qb    = (bf16_t*)(base + 2 * SLOT);
  bf16_t* kb    = (bf16_t*)(base + 3 * SLOT);
  bf16_t* vt    = (bf16_t*)(base + 4 * SLOT);
  bf16_t* ob    = (bf16_t*)(base + 5 * SLOT);
  bf16_t* h2    = h1;
  bf16_t* g     = qb;
  float*  x1    = out;

  auto cvt = [&](const float* in, bf16_t* o, size_t n) {
    int n8 = (int)(n / 8);
    cvt_kernel<<<(n8 + 255) / 256, 256, 0, stream>>>(in, o, n8);
  };

  rmsnorm_kernel<<<B_ * S_, 256, 0, stream>>>(x, g1, h1);

  // fused QKV + RoPE: [rope(q) | rope(k) | v^T] = h1 @ [wq;wk;wv]^T
  cvt(wq, wslot, ND);
  cvt(wk, wslot + ND, ND);
  cvt(wv, wslot + 2 * ND, ND);
  const int gqkv3 = (8192 / 128) * (6144 / 256);   // 1536 blocks
  gemm256h<4><<<gqkv3, 512, 0, stream>>>(h1, wslot, nullptr, nullptr,
                                         qb, kb, vt, nullptr, 8192, 6144, 2048);

  dim3 ga(S_ / 64, H_, B_);
  attn_kernel<<<ga, 256, 0, stream>>>(qb, kb, vt, ob);

  const int gd = (8192 / 128) * (2048 / 256);      // 512 blocks
  cvt(wo, wslot, ND);
  gemm256h<1><<<gd, 512, 0, stream>>>(ob, wslot, x, nullptr,
                                      nullptr, nullptr, nullptr, x1, 8192, 2048, 2048);

  rmsnorm_kernel<<<B_ * S_, 256, 0, stream>>>(x1, g2, h2);

  const int gffh = (8192 / 128) * (8192 / 256);    // 2048 blocks
  cvt(w1, wslot, NF);
  gemm256h<0><<<gffh, 512, 0, stream>>>(h2, wslot, nullptr, nullptr,
                                        g, nullptr, nullptr, nullptr, 8192, 8192, 2048);

  cvt(w3, wslot, NF);
  gemm256h<2><<<gffh, 512, 0, stream>>>(h2, wslot, nullptr, g,
                                        g, nullptr, nullptr, nullptr, 8192, 8192, 2048);

  cvt(w2, wslot, NF);
  gemm256h<1><<<gd, 512, 0, stream>>>(g, wslot, x1, nullptr,
                                      nullptr, nullptr, nullptr, x1, 8192, 2048, 8192);
}